// Round 2
// baseline (395.106 us; speedup 1.0000x reference)
//
#include <hip/hip_runtime.h>
#include <hip/hip_bf16.h>

// FlexibleGCN forward on MI355X — Round 10:
//  * Split-feature 2-pass aggregation: hp stored as two 6.4MB half-buffers
//    (features 0..31 / 32..63). Each agg pass gathers 64B rows from a
//    working set that mostly fits per-XCD L2 (4MB) -> fetch ~165MB -> ~100MB
//    per layer. 8-lane groups x uint2 loads = 8 edges per wave-instruction
//    (4x fewer gather instrs + more MLP than R9's 2 edges/wave).
//  * gemm1/gemm2 write split bf16 hp; gemm2 reads split bf16 h1.
//  * FC head fused into agg2 pass B (stages row in LDS, re-reads A-half).

constexpr int IN_DIM  = 128;
constexpr int HDIM    = 64;
constexpr int NBLK_A  = 256;   // blocks in pass A (must match histg stride)
constexpr int BSH     = 8;     // bucket shift: 256 nodes per bucket
constexpr int MAXNB   = 512;   // max buckets supported (N <= 131072)

__device__ __forceinline__ float bf2f(unsigned int u) {
    return __uint_as_float(u << 16);
}
__device__ __forceinline__ unsigned short f2bf_bits(float f) {
    __hip_bfloat16 b = __float2bfloat16(f);
    return *(unsigned short*)&b;
}

// ---------- CSR build ----------

__global__ void binA_count(const int* __restrict__ dst, int* __restrict__ histg,
                           int E, int NB, int chunk) {
    __shared__ int h[MAXNB];
    for (int i = threadIdx.x; i < NB; i += 256) h[i] = 0;
    __syncthreads();
    int beg = blockIdx.x * chunk;
    int end = min(E, beg + chunk);
    for (int e = beg + threadIdx.x; e < end; e += 256)
        atomicAdd(&h[dst[e] >> BSH], 1);
    __syncthreads();
    for (int i = threadIdx.x; i < NB; i += 256)
        histg[i * NBLK_A + blockIdx.x] = h[i];
}

__global__ void binA_scanblocks(int* __restrict__ histg, int* __restrict__ btot) {
    __shared__ int sm[NBLK_A];
    int tid = threadIdx.x;
    int v = histg[blockIdx.x * NBLK_A + tid];
    sm[tid] = v;
    __syncthreads();
    for (int off = 1; off < NBLK_A; off <<= 1) {
        int t = (tid >= off) ? sm[tid - off] : 0;
        __syncthreads();
        sm[tid] += t;
        __syncthreads();
    }
    histg[blockIdx.x * NBLK_A + tid] = sm[tid] - v;   // exclusive
    if (tid == NBLK_A - 1) btot[blockIdx.x] = sm[tid];
}

__global__ void binA_scanbuckets(const int* __restrict__ btot, int* __restrict__ bucketbase,
                                 int NB) {
    __shared__ int sm[MAXNB];
    int tid = threadIdx.x;    // blockDim = MAXNB
    int v = (tid < NB) ? btot[tid] : 0;
    sm[tid] = v;
    __syncthreads();
    for (int off = 1; off < MAXNB; off <<= 1) {
        int t = (tid >= off) ? sm[tid - off] : 0;
        __syncthreads();
        sm[tid] += t;
        __syncthreads();
    }
    if (tid < NB) bucketbase[tid] = sm[tid] - v;
    if (tid == MAXNB - 1) bucketbase[NB] = sm[tid];   // == E
}

__global__ void binA_scatter(const int* __restrict__ src, const int* __restrict__ dst,
                             const int* __restrict__ histg, const int* __restrict__ bucketbase,
                             int* __restrict__ staging, int E, int NB, int chunk) {
    __shared__ int cur[MAXNB];
    for (int i = threadIdx.x; i < NB; i += 256)
        cur[i] = bucketbase[i] + histg[i * NBLK_A + blockIdx.x];
    __syncthreads();
    int beg = blockIdx.x * chunk;
    int end = min(E, beg + chunk);
    for (int e = beg + threadIdx.x; e < end; e += 256) {
        int s = src[e];
        int d = dst[e];
        int pos = atomicAdd(&cur[d >> BSH], 1);
        staging[pos] = (s << BSH) | (d & 255);    // src<2^17, local dst 8 bits
    }
}

__global__ void binB_finalize(const int* __restrict__ staging, const int* __restrict__ bucketbase,
                              int* __restrict__ rowptr, int* __restrict__ esrc,
                              float* __restrict__ dinv, int N, int NB) {
    __shared__ int cnt[256], sm[256], cur[256];
    int tid = threadIdx.x;
    int b = blockIdx.x;
    int node0 = b << BSH;
    int nloc = min(256, N - node0);
    int ebeg = bucketbase[b], eend = bucketbase[b + 1];
    cnt[tid] = 0;
    __syncthreads();
    for (int e = ebeg + tid; e < eend; e += 256)
        atomicAdd(&cnt[staging[e] & 255], 1);
    __syncthreads();
    int v = cnt[tid];
    sm[tid] = v;
    __syncthreads();
    for (int off = 1; off < 256; off <<= 1) {
        int t = (tid >= off) ? sm[tid - off] : 0;
        __syncthreads();
        sm[tid] += t;
        __syncthreads();
    }
    int excl = sm[tid] - v;
    cur[tid] = excl;
    __syncthreads();
    if (tid < nloc) {
        rowptr[node0 + tid] = ebeg + excl;
        dinv[node0 + tid] = rsqrtf((float)v + 1.0f);   // +1 self-loop
    }
    if (b == 0 && tid == 0) rowptr[N] = bucketbase[NB];
    for (int e = ebeg + tid; e < eend; e += 256) {
        int p = staging[e];
        int pos = ebeg + atomicAdd(&cur[p & 255], 1);
        esrc[pos] = p >> BSH;
    }
}

// ---------- dense layers ----------

// Y = (X @ W) * dinv[row], written as split bf16 halves YA (cols 0..31) /
// YB (cols 32..63). X is fp32 [n][K] (SPLITIN=false) or split bf16 halves
// XA/XB (SPLITIN=true, K=64). 256 thr, tile 128x64, thread 8x4, KC=32.
template<int K, bool IBF16, bool SPLITIN>
__device__ __forceinline__ void gemm_body(
        const void* __restrict__ XAv, const void* __restrict__ XBv,
        const float* __restrict__ W, const float* __restrict__ dinv,
        unsigned short* __restrict__ YA, unsigned short* __restrict__ YB, int n) {
    constexpr int KC = 32;
    constexpr int XSTR = 132;                 // floats
    __shared__ float Xt[KC * XSTR];           // 16.9 KB
    __shared__ float Ws[KC * 64];             // 8 KB
    const int tid = threadIdx.x;
    const int node0 = blockIdx.x * 128;
    const int r0 = (tid >> 4) * 8;            // 0..120
    const int c0 = (tid & 15) * 4;            // 0..60

    float acc[8][4];
#pragma unroll
    for (int a = 0; a < 8; ++a)
#pragma unroll
        for (int b = 0; b < 4; ++b) acc[a][b] = 0.f;

    for (int kc = 0; kc < K; kc += KC) {
        __syncthreads();
#pragma unroll
        for (int i = 0; i < 4; ++i) {
            int s = tid + i * 256;
            int row = s >> 3;
            int kq = s & 7;
            int grow = node0 + row;
            float4 v = make_float4(0.f, 0.f, 0.f, 0.f);
            if (grow < n) {
                if (IBF16) {
                    const unsigned short* xb = SPLITIN
                        ? (const unsigned short*)(kc == 0 ? XAv : XBv)
                        : (const unsigned short*)XAv;
                    size_t off = SPLITIN ? ((size_t)grow * 32 + kq * 4)
                                         : ((size_t)grow * K + kc + kq * 4);
                    uint2 u = *(const uint2*)&xb[off];
                    v.x = bf2f(u.x & 0xffff); v.y = bf2f(u.x >> 16);
                    v.z = bf2f(u.y & 0xffff); v.w = bf2f(u.y >> 16);
                } else {
                    v = *(const float4*)&((const float*)XAv)[(size_t)grow * K + kc + kq * 4];
                }
            }
            Xt[(kq * 4 + 0) * XSTR + row] = v.x;
            Xt[(kq * 4 + 1) * XSTR + row] = v.y;
            Xt[(kq * 4 + 2) * XSTR + row] = v.z;
            Xt[(kq * 4 + 3) * XSTR + row] = v.w;
        }
#pragma unroll
        for (int i = 0; i < 2; ++i) {
            int s = tid + i * 256;
            *(float4*)&Ws[s * 4] = *(const float4*)&W[(size_t)kc * 64 + s * 4];
        }
        __syncthreads();
#pragma unroll
        for (int kk = 0; kk < KC; kk += 4) {
            float4 xa[4][2];
            float4 wv[4];
#pragma unroll
            for (int i = 0; i < 4; ++i) {
                xa[i][0] = *(const float4*)&Xt[(kk + i) * XSTR + r0];
                xa[i][1] = *(const float4*)&Xt[(kk + i) * XSTR + r0 + 4];
                wv[i]    = *(const float4*)&Ws[(kk + i) * 64 + c0];
            }
#pragma unroll
            for (int i = 0; i < 4; ++i) {
                const float* xp = (const float*)&xa[i][0];
                const float* wp = (const float*)&wv[i];
#pragma unroll
                for (int rr = 0; rr < 8; ++rr)
#pragma unroll
                    for (int cc = 0; cc < 4; ++cc)
                        acc[rr][cc] += xp[rr] * wp[cc];
            }
        }
    }
#pragma unroll
    for (int rr = 0; rr < 8; ++rr) {
        int node = node0 + r0 + rr;
        if (node < n) {
            float d = dinv[node];
            __hip_bfloat16 vb[4];
#pragma unroll
            for (int cc = 0; cc < 4; ++cc)
                vb[cc] = __float2bfloat16(acc[rr][cc] * d);
            unsigned short* Yb = (c0 < 32) ? YA : YB;
            *(uint2*)&Yb[(size_t)node * 32 + (c0 & 31)] = *(uint2*)vb;
        }
    }
}

__global__ __launch_bounds__(256, 4) void gemm1_kernel(
        const float* X, const float* W, const float* dinv,
        unsigned short* YA, unsigned short* YB, int n) {
    gemm_body<IN_DIM, false, false>(X, nullptr, W, dinv, YA, YB, n);
}
__global__ __launch_bounds__(256, 4) void gemm2_kernel(
        const unsigned short* XA, const unsigned short* XB,
        const float* W, const float* dinv,
        unsigned short* YA, unsigned short* YB, int n) {
    gemm_body<HDIM, true, true>(XA, XB, W, dinv, YA, YB, n);
}

// ---------- aggregation: one feature-half per pass ----------
// One wave per node. Lane = (g, j): group g=lane>>3 handles edge slot g,
// lane j=lane&7 covers features 4j..4j+3 of this half (uint2 = 4 bf16).
// 8 edges per gather instruction, 16 edges in flight (2 batches).
// PASS: 0 = features 0..31, 1 = 32..63 (bias offset + emb column offset).
// OBF16: write bf16 half-row (h1A/h1B); else fp32 into emb[N][64].
// FC (PASS=1, fp32 out): stage full emb row in LDS, compute logits.
template<int PASS, bool OBF16, bool FC>
__global__ __launch_bounds__(256) void agg_pass(
        const uint2* __restrict__ hpx, const int* __restrict__ esrc,
        const int* __restrict__ rowptr, const float* __restrict__ dinv,
        const float* __restrict__ bias, void* __restrict__ out,
        const float* __restrict__ Wfc, const float* __restrict__ bfc,
        float* __restrict__ logits, int n) {
    __shared__ float hsm[4][64];
    const int w = threadIdx.x >> 6;
    const int node = blockIdx.x * 4 + w;
    const int lane = threadIdx.x & 63;
    const int g = lane >> 3;
    const int j = lane & 7;
    const bool valid = node < n;

    if (valid) {
        const int beg = rowptr[node], end = rowptr[node + 1];
        float a0 = 0.f, a1 = 0.f, a2 = 0.f, a3 = 0.f;
        if (g == 0) {   // self-loop counted once (group 0)
            uint2 u = hpx[(size_t)node * 8 + j];
            a0 = bf2f(u.x & 0xffff); a1 = bf2f(u.x >> 16);
            a2 = bf2f(u.y & 0xffff); a3 = bf2f(u.y >> 16);
        }
        int k = beg;
        for (; k + 16 <= end; k += 16) {
            int s0 = esrc[k + g];
            int s1 = esrc[k + 8 + g];
            uint2 u0 = hpx[(size_t)s0 * 8 + j];
            uint2 u1 = hpx[(size_t)s1 * 8 + j];
            a0 += bf2f(u0.x & 0xffff) + bf2f(u1.x & 0xffff);
            a1 += bf2f(u0.x >> 16)    + bf2f(u1.x >> 16);
            a2 += bf2f(u0.y & 0xffff) + bf2f(u1.y & 0xffff);
            a3 += bf2f(u0.y >> 16)    + bf2f(u1.y >> 16);
        }
        if (k < end) {   // 1..15 remaining: one predicated 16-slot batch
            int e0 = k + g, e1 = k + 8 + g;
            int s0 = esrc[min(e0, end - 1)];
            int s1 = esrc[min(e1, end - 1)];
            uint2 u0 = hpx[(size_t)s0 * 8 + j];
            uint2 u1 = hpx[(size_t)s1 * 8 + j];
            if (e0 < end) {
                a0 += bf2f(u0.x & 0xffff); a1 += bf2f(u0.x >> 16);
                a2 += bf2f(u0.y & 0xffff); a3 += bf2f(u0.y >> 16);
            }
            if (e1 < end) {
                a0 += bf2f(u1.x & 0xffff); a1 += bf2f(u1.x >> 16);
                a2 += bf2f(u1.y & 0xffff); a3 += bf2f(u1.y >> 16);
            }
        }
        // reduce across the 8 edge groups (j preserved)
#pragma unroll
        for (int st = 8; st <= 32; st <<= 1) {
            a0 += __shfl_xor(a0, st, 64);
            a1 += __shfl_xor(a1, st, 64);
            a2 += __shfl_xor(a2, st, 64);
            a3 += __shfl_xor(a3, st, 64);
        }
        const float d = dinv[node];
        const float v0 = fmaxf(fmaf(d, a0, bias[PASS * 32 + 4 * j + 0]), 0.f);
        const float v1 = fmaxf(fmaf(d, a1, bias[PASS * 32 + 4 * j + 1]), 0.f);
        const float v2 = fmaxf(fmaf(d, a2, bias[PASS * 32 + 4 * j + 2]), 0.f);
        const float v3 = fmaxf(fmaf(d, a3, bias[PASS * 32 + 4 * j + 3]), 0.f);

        if (g == 0) {
            if (OBF16) {
                unsigned int p0 = (unsigned int)f2bf_bits(v0) | ((unsigned int)f2bf_bits(v1) << 16);
                unsigned int p1 = (unsigned int)f2bf_bits(v2) | ((unsigned int)f2bf_bits(v3) << 16);
                ((uint2*)out)[(size_t)node * 8 + j] = make_uint2(p0, p1);
            } else {
                ((float4*)out)[(size_t)node * 16 + PASS * 8 + j] = make_float4(v0, v1, v2, v3);
            }
        }
        if (FC) {
            if (g == 0) {           // B-half from registers
                hsm[w][32 + 4 * j + 0] = v0;
                hsm[w][32 + 4 * j + 1] = v1;
                hsm[w][32 + 4 * j + 2] = v2;
                hsm[w][32 + 4 * j + 3] = v3;
            } else if (g == 1) {    // A-half re-read (written by pass A kernel)
                float4 f = ((const float4*)out)[(size_t)node * 16 + j];
                hsm[w][4 * j + 0] = f.x;
                hsm[w][4 * j + 1] = f.y;
                hsm[w][4 * j + 2] = f.z;
                hsm[w][4 * j + 3] = f.w;
            }
        }
    } else if (FC) {
        hsm[w][lane] = 0.f;
    }

    if (FC) {
        __syncthreads();
        float acc = bfc[lane];
        const float* hrow = hsm[w];
#pragma unroll 16
        for (int f = 0; f < 64; ++f)
            acc += hrow[f] * Wfc[(size_t)f * 64 + lane];
        if (valid) logits[(size_t)node * 64 + lane] = acc;
    }
}

extern "C" void kernel_launch(void* const* d_in, const int* in_sizes, int n_in,
                              void* d_out, int out_size, void* d_ws, size_t ws_size,
                              hipStream_t stream) {
    const float* x   = (const float*)d_in[0];
    const float* W1  = (const float*)d_in[1];
    const float* b1  = (const float*)d_in[2];
    const float* W2  = (const float*)d_in[3];
    const float* b2  = (const float*)d_in[4];
    const float* Wfc = (const float*)d_in[5];
    const float* bfc = (const float*)d_in[6];
    const int*  eidx = (const int*)d_in[7];

    const int N = in_sizes[0] / IN_DIM;     // 100000
    const int E = in_sizes[7] / 2;          // 1600000
    const int* src = eidx;
    const int* dst = eidx + E;

    const int NB    = (N + 255) >> BSH;     // 391 buckets
    const int chunk = (E + NBLK_A - 1) / NBLK_A;

    // ws layout (ints, every region rounded to 4 ints = 16B alignment):
    // rowptr[N+2] | dinv[N] | histg[NB*256] | btot[512] | bucketbase[512] |
    // esrc[E] | hpA[N*16] | hpB[N*16] | h1A[N*16] | h1B[N*16]
    // staging int[E] aliases hpA (+hpB) — dead before gemm1 writes hp.
    int* p = (int*)d_ws;
    int* rowptr = p;                 p += (size_t)((N + 2 + 3) & ~3);
    float* dinv = (float*)p;         p += (size_t)((N + 3) & ~3);
    int* histg = p;                  p += (size_t)((NB * NBLK_A + 3) & ~3);
    int* btot = p;                   p += 512;
    int* bucketbase = p;             p += 512;
    int* esrc = p;                   p += (size_t)((E + 3) & ~3);
    unsigned short* hpA = (unsigned short*)p;  p += (size_t)N * 16;
    unsigned short* hpB = (unsigned short*)p;  p += (size_t)N * 16;
    unsigned short* h1A = (unsigned short*)p;  p += (size_t)N * 16;
    unsigned short* h1B = (unsigned short*)p;  p += (size_t)N * 16;
    int* staging = (int*)hpA;        // E ints fit in hpA+hpB (12.8MB >= 6.4MB)

    float* emb    = (float*)d_out;
    float* logits = emb + (size_t)N * HDIM;

    // ---- CSR build (shared by both conv layers) ----
    binA_count<<<NBLK_A, 256, 0, stream>>>(dst, histg, E, NB, chunk);
    binA_scanblocks<<<NB, NBLK_A, 0, stream>>>(histg, btot);
    binA_scanbuckets<<<1, MAXNB, 0, stream>>>(btot, bucketbase, NB);
    binA_scatter<<<NBLK_A, 256, 0, stream>>>(src, dst, histg, bucketbase, staging, E, NB, chunk);
    binB_finalize<<<NB, 256, 0, stream>>>(staging, bucketbase, rowptr, esrc, dinv, N, NB);

    const int gBlocks = (N + 127) / 128;
    const int aBlocks = (N + 3) / 4;

    // ---- layer 1 ----
    gemm1_kernel<<<gBlocks, 256, 0, stream>>>(x, W1, dinv, hpA, hpB, N);
    agg_pass<0, true, false><<<aBlocks, 256, 0, stream>>>(
        (const uint2*)hpA, esrc, rowptr, dinv, b1, h1A, nullptr, nullptr, nullptr, N);
    agg_pass<1, true, false><<<aBlocks, 256, 0, stream>>>(
        (const uint2*)hpB, esrc, rowptr, dinv, b1, h1B, nullptr, nullptr, nullptr, N);

    // ---- layer 2 ----
    gemm2_kernel<<<gBlocks, 256, 0, stream>>>(h1A, h1B, W2, dinv, hpA, hpB, N);
    agg_pass<0, false, false><<<aBlocks, 256, 0, stream>>>(
        (const uint2*)hpA, esrc, rowptr, dinv, b2, emb, nullptr, nullptr, nullptr, N);
    agg_pass<1, false, true><<<aBlocks, 256, 0, stream>>>(
        (const uint2*)hpB, esrc, rowptr, dinv, b2, emb, Wfc, bfc, logits, N);
}

// Round 4
// 315.366 us; speedup vs baseline: 1.2529x; 1.2529x over previous
//
#include <hip/hip_runtime.h>
#include <hip/hip_bf16.h>

// FlexibleGCN forward on MI355X — Round 12 (R11 compile fix):
//  * CSR-vector aggregation: 8-lane group per node, lane = uint4 (8 bf16
//    feats of the full 64-wide row), depth-8 unroll -> 8x16B gathers in
//    flight per lane; one gather instr covers 8 edges (4x fewer VMEM than
//    R9, ~45% less VALU). No cross-lane reduce.
//  * Edge lists padded to multiples of 8 with src=N pointing at a zeroed
//    hp row -> tail-free main loop (pad gathers are L1 hits).
//  * rows[] = int2(beg,end) per node (padded CSR has inter-bucket gaps).
//  * nontemporal loads on esrc only (scalar int — float4 rejected by the
//    builtin, was R11's compile error). FC head separate (R8-proven).

constexpr int IN_DIM  = 128;
constexpr int HDIM    = 64;
constexpr int NBLK_A  = 256;   // blocks in pass A (must match histg stride)
constexpr int BSH     = 8;     // bucket shift: 256 nodes per bucket
constexpr int MAXNB   = 512;   // max buckets supported (N <= 131072)
constexpr int PADSLK  = 1792;  // per-bucket esrc slack: 256 nodes x 7 max pad

__device__ __forceinline__ float bf2f(unsigned int u) {
    return __uint_as_float(u << 16);
}
__device__ __forceinline__ unsigned short f2bf_bits(float f) {
    __hip_bfloat16 b = __float2bfloat16(f);
    return *(unsigned short*)&b;
}

// ---------- CSR build ----------

__global__ void binA_count(const int* __restrict__ dst, int* __restrict__ histg,
                           int E, int NB, int chunk) {
    __shared__ int h[MAXNB];
    for (int i = threadIdx.x; i < NB; i += 256) h[i] = 0;
    __syncthreads();
    int beg = blockIdx.x * chunk;
    int end = min(E, beg + chunk);
    for (int e = beg + threadIdx.x; e < end; e += 256)
        atomicAdd(&h[dst[e] >> BSH], 1);
    __syncthreads();
    for (int i = threadIdx.x; i < NB; i += 256)
        histg[i * NBLK_A + blockIdx.x] = h[i];
}

__global__ void binA_scanblocks(int* __restrict__ histg, int* __restrict__ btot) {
    __shared__ int sm[NBLK_A];
    int tid = threadIdx.x;
    int v = histg[blockIdx.x * NBLK_A + tid];
    sm[tid] = v;
    __syncthreads();
    for (int off = 1; off < NBLK_A; off <<= 1) {
        int t = (tid >= off) ? sm[tid - off] : 0;
        __syncthreads();
        sm[tid] += t;
        __syncthreads();
    }
    histg[blockIdx.x * NBLK_A + tid] = sm[tid] - v;   // exclusive
    if (tid == NBLK_A - 1) btot[blockIdx.x] = sm[tid];
}

__global__ void binA_scanbuckets(const int* __restrict__ btot, int* __restrict__ bucketbase,
                                 int NB) {
    __shared__ int sm[MAXNB];
    int tid = threadIdx.x;    // blockDim = MAXNB
    int v = (tid < NB) ? btot[tid] : 0;
    sm[tid] = v;
    __syncthreads();
    for (int off = 1; off < MAXNB; off <<= 1) {
        int t = (tid >= off) ? sm[tid - off] : 0;
        __syncthreads();
        sm[tid] += t;
        __syncthreads();
    }
    if (tid < NB) bucketbase[tid] = sm[tid] - v;
    if (tid == MAXNB - 1) bucketbase[NB] = sm[tid];   // == E
}

__global__ void binA_scatter(const int* __restrict__ src, const int* __restrict__ dst,
                             const int* __restrict__ histg, const int* __restrict__ bucketbase,
                             int* __restrict__ staging, int E, int NB, int chunk) {
    __shared__ int cur[MAXNB];
    for (int i = threadIdx.x; i < NB; i += 256)
        cur[i] = bucketbase[i] + histg[i * NBLK_A + blockIdx.x];
    __syncthreads();
    int beg = blockIdx.x * chunk;
    int end = min(E, beg + chunk);
    for (int e = beg + threadIdx.x; e < end; e += 256) {
        int s = src[e];
        int d = dst[e];
        int pos = atomicAdd(&cur[d >> BSH], 1);
        staging[pos] = (s << BSH) | (d & 255);    // src<2^17, local dst 8 bits
    }
}

// Builds padded CSR: per-node range rounded up to a multiple of 8; pad
// slots point at node N (whose hp row is zeroed here). rows[n]=(beg,end).
__global__ void binB_finalize(const int* __restrict__ staging, const int* __restrict__ bucketbase,
                              int2* __restrict__ rows, int* __restrict__ esrc,
                              float* __restrict__ dinv, unsigned int* __restrict__ hp_rowN,
                              int N, int NB) {
    __shared__ int cnt[256], sm[256], cur[256];
    int tid = threadIdx.x;
    int b = blockIdx.x;
    int node0 = b << BSH;
    int nloc = min(256, N - node0);
    int ebeg = bucketbase[b], eend = bucketbase[b + 1];
    int ebegP = ebeg + b * PADSLK;            // padded bucket base
    cnt[tid] = 0;
    __syncthreads();
    for (int e = ebeg + tid; e < eend; e += 256)
        atomicAdd(&cnt[staging[e] & 255], 1);
    __syncthreads();
    int v = cnt[tid];
    int pv = (v + 7) & ~7;                    // padded count
    sm[tid] = pv;
    __syncthreads();
    for (int off = 1; off < 256; off <<= 1) {
        int t = (tid >= off) ? sm[tid - off] : 0;
        __syncthreads();
        sm[tid] += t;
        __syncthreads();
    }
    int excl = sm[tid] - pv;                  // padded exclusive offset
    cur[tid] = excl;
    __syncthreads();
    if (tid < nloc) {
        rows[node0 + tid] = make_int2(ebegP + excl, ebegP + excl + pv);
        dinv[node0 + tid] = rsqrtf((float)v + 1.0f);   // +1 self-loop
        for (int q = v; q < pv; ++q)          // fill pad slots -> zero row
            esrc[ebegP + excl + q] = N;
    }
    if (b == 0 && tid < 32) hp_rowN[tid] = 0u;         // zero hp row N (128B)
    for (int e = ebeg + tid; e < eend; e += 256) {
        int p = staging[e];
        int pos = ebegP + atomicAdd(&cur[p & 255], 1);
        esrc[pos] = p >> BSH;
    }
}

// ---------- dense layers ----------

// Y[n][64] = X[n][K] @ W[K][64]; optional *dinv[row], optional +bias.
// 256 threads, tile 128 rows x 64 cols; thread = 8x4 micro-tile; KC=32.
template<int K, bool IBF16, bool SCALE, bool BIAS, bool OBF16>
__device__ __forceinline__ void gemm_body(
        const void* __restrict__ Xv, const float* __restrict__ W,
        const float* __restrict__ bias, const float* __restrict__ dinv,
        void* __restrict__ Yv, int n) {
    constexpr int KC = 32;
    constexpr int XSTR = 132;                 // floats
    __shared__ float Xt[KC * XSTR];           // 16.9 KB
    __shared__ float Ws[KC * 64];             // 8 KB
    const int tid = threadIdx.x;
    const int node0 = blockIdx.x * 128;
    const int r0 = (tid >> 4) * 8;            // 0..120
    const int c0 = (tid & 15) * 4;            // 0..60

    float acc[8][4];
#pragma unroll
    for (int a = 0; a < 8; ++a)
#pragma unroll
        for (int b = 0; b < 4; ++b) acc[a][b] = 0.f;

    for (int kc = 0; kc < K; kc += KC) {
        __syncthreads();
#pragma unroll
        for (int i = 0; i < 4; ++i) {
            int s = tid + i * 256;
            int row = s >> 3;
            int kq = s & 7;
            int grow = node0 + row;
            float4 v = make_float4(0.f, 0.f, 0.f, 0.f);
            if (grow < n) {
                if (IBF16) {
                    uint2 u = *(const uint2*)&((const unsigned short*)Xv)[(size_t)grow * K + kc + kq * 4];
                    v.x = bf2f(u.x & 0xffff); v.y = bf2f(u.x >> 16);
                    v.z = bf2f(u.y & 0xffff); v.w = bf2f(u.y >> 16);
                } else {
                    v = *(const float4*)&((const float*)Xv)[(size_t)grow * K + kc + kq * 4];
                }
            }
            Xt[(kq * 4 + 0) * XSTR + row] = v.x;
            Xt[(kq * 4 + 1) * XSTR + row] = v.y;
            Xt[(kq * 4 + 2) * XSTR + row] = v.z;
            Xt[(kq * 4 + 3) * XSTR + row] = v.w;
        }
#pragma unroll
        for (int i = 0; i < 2; ++i) {
            int s = tid + i * 256;
            *(float4*)&Ws[s * 4] = *(const float4*)&W[(size_t)kc * 64 + s * 4];
        }
        __syncthreads();
#pragma unroll
        for (int kk = 0; kk < KC; kk += 4) {
            float4 xa[4][2];
            float4 wv[4];
#pragma unroll
            for (int i = 0; i < 4; ++i) {
                xa[i][0] = *(const float4*)&Xt[(kk + i) * XSTR + r0];
                xa[i][1] = *(const float4*)&Xt[(kk + i) * XSTR + r0 + 4];
                wv[i]    = *(const float4*)&Ws[(kk + i) * 64 + c0];
            }
#pragma unroll
            for (int i = 0; i < 4; ++i) {
                const float* xp = (const float*)&xa[i][0];
                const float* wp = (const float*)&wv[i];
#pragma unroll
                for (int rr = 0; rr < 8; ++rr)
#pragma unroll
                    for (int cc = 0; cc < 4; ++cc)
                        acc[rr][cc] += xp[rr] * wp[cc];
            }
        }
    }
#pragma unroll
    for (int rr = 0; rr < 8; ++rr) {
        int node = node0 + r0 + rr;
        if (node < n) {
            float d = SCALE ? dinv[node] : 1.0f;
            float t[4];
#pragma unroll
            for (int cc = 0; cc < 4; ++cc) {
                float v = acc[rr][cc];
                if (BIAS) v += bias[c0 + cc];
                t[cc] = v * d;
            }
            if (OBF16) {
                __hip_bfloat16 vb[4];
#pragma unroll
                for (int cc = 0; cc < 4; ++cc) vb[cc] = __float2bfloat16(t[cc]);
                *(uint2*)&((__hip_bfloat16*)Yv)[(size_t)node * 64 + c0] = *(uint2*)vb;
            } else {
                *(float4*)&((float*)Yv)[(size_t)node * 64 + c0] = *(float4*)t;
            }
        }
    }
}

__global__ __launch_bounds__(256, 4) void gemm1_kernel(
        const float* X, const float* W, const float* dinv, void* Y, int n) {
    gemm_body<IN_DIM, false, true, false, true>(X, W, nullptr, dinv, Y, n);
}
__global__ __launch_bounds__(256, 4) void gemm2_kernel(
        const void* X, const float* W, const float* dinv, void* Y, int n) {
    gemm_body<HDIM, true, true, false, true>(X, W, nullptr, dinv, Y, n);
}
__global__ __launch_bounds__(256, 4) void fc_kernel(
        const float* X, const float* W, const float* bias, void* Y, int n) {
    gemm_body<HDIM, false, false, true, false>(X, W, bias, nullptr, Y, n);
}

// ---------- aggregation: CSR-vector, 8 lanes per node ----------
// Wave = 8 nodes x 8 lanes. Lane j holds feats 8j..8j+7 (uint4 = 16B of the
// 128B bf16 row). Depth-8 unroll: 8 independent row-gathers in flight; one
// gather instruction covers 8 edges' full rows (8 groups x 128B coalesced).
// Edge lists are padded to %8 with src=N (zeroed row) -> no tail.
template<bool OBF16>
__global__ __launch_bounds__(256) void agg_kernel(
        const uint4* __restrict__ hp4, const int* __restrict__ esrc,
        const int2* __restrict__ rows, const float* __restrict__ dinv,
        const float* __restrict__ bias, void* __restrict__ out, int n) {
    const int lane = threadIdx.x & 63;
    const int j = lane & 7;
    const int node = blockIdx.x * 32 + (threadIdx.x >> 6) * 8 + (lane >> 3);
    if (node >= n) return;
    const int2 be = rows[node];

    float acc[8];
    {   // self-loop: own row
        uint4 u = hp4[(size_t)node * 8 + j];
        acc[0] = bf2f(u.x & 0xffff); acc[1] = bf2f(u.x >> 16);
        acc[2] = bf2f(u.y & 0xffff); acc[3] = bf2f(u.y >> 16);
        acc[4] = bf2f(u.z & 0xffff); acc[5] = bf2f(u.z >> 16);
        acc[6] = bf2f(u.w & 0xffff); acc[7] = bf2f(u.w >> 16);
    }
    for (int k = be.x; k < be.y; k += 8) {
        int s[8];
#pragma unroll
        for (int i = 0; i < 8; ++i)
            s[i] = __builtin_nontemporal_load(&esrc[k + i]);
        uint4 u[8];
#pragma unroll
        for (int i = 0; i < 8; ++i)
            u[i] = hp4[(size_t)s[i] * 8 + j];
#pragma unroll
        for (int i = 0; i < 8; ++i) {
            acc[0] += bf2f(u[i].x & 0xffff); acc[1] += bf2f(u[i].x >> 16);
            acc[2] += bf2f(u[i].y & 0xffff); acc[3] += bf2f(u[i].y >> 16);
            acc[4] += bf2f(u[i].z & 0xffff); acc[5] += bf2f(u[i].z >> 16);
            acc[6] += bf2f(u[i].w & 0xffff); acc[7] += bf2f(u[i].w >> 16);
        }
    }
    const float d = dinv[node];
    float o[8];
#pragma unroll
    for (int t = 0; t < 8; ++t)
        o[t] = fmaxf(fmaf(d, acc[t], bias[8 * j + t]), 0.f);

    if (OBF16) {
        uint4 pk;
        pk.x = (unsigned)f2bf_bits(o[0]) | ((unsigned)f2bf_bits(o[1]) << 16);
        pk.y = (unsigned)f2bf_bits(o[2]) | ((unsigned)f2bf_bits(o[3]) << 16);
        pk.z = (unsigned)f2bf_bits(o[4]) | ((unsigned)f2bf_bits(o[5]) << 16);
        pk.w = (unsigned)f2bf_bits(o[6]) | ((unsigned)f2bf_bits(o[7]) << 16);
        ((uint4*)out)[(size_t)node * 8 + j] = pk;
    } else {
        ((float4*)out)[(size_t)node * 16 + 2 * j]     = make_float4(o[0], o[1], o[2], o[3]);
        ((float4*)out)[(size_t)node * 16 + 2 * j + 1] = make_float4(o[4], o[5], o[6], o[7]);
    }
}

extern "C" void kernel_launch(void* const* d_in, const int* in_sizes, int n_in,
                              void* d_out, int out_size, void* d_ws, size_t ws_size,
                              hipStream_t stream) {
    const float* x   = (const float*)d_in[0];
    const float* W1  = (const float*)d_in[1];
    const float* b1  = (const float*)d_in[2];
    const float* W2  = (const float*)d_in[3];
    const float* b2  = (const float*)d_in[4];
    const float* Wfc = (const float*)d_in[5];
    const float* bfc = (const float*)d_in[6];
    const int*  eidx = (const int*)d_in[7];

    const int N = in_sizes[0] / IN_DIM;     // 100000
    const int E = in_sizes[7] / 2;          // 1600000
    const int* src = eidx;
    const int* dst = eidx + E;

    const int NB    = (N + 255) >> BSH;     // 391 buckets
    const int chunk = (E + NBLK_A - 1) / NBLK_A;
    const int EP    = E + NB * PADSLK;      // padded esrc capacity

    // ws layout (ints, regions 16B-aligned):
    // rows[N] (int2) | dinv[N] | histg[NB*256] | btot[512] | bucketbase[512]
    //   | esrc[EP] | hp[(N+1)*32] (bf16 rows, row N = zero) | h1[N*32]
    // staging int[E] aliases hp (dead before gemm1 writes hp).
    int* p = (int*)d_ws;
    int2* rows = (int2*)p;           p += (size_t)2 * N + 2;
    float* dinv = (float*)p;         p += (size_t)((N + 3) & ~3);
    int* histg = p;                  p += (size_t)((NB * NBLK_A + 3) & ~3);
    int* btot = p;                   p += 512;
    int* bucketbase = p;             p += 512;
    int* esrc = p;                   p += (size_t)((EP + 3) & ~3);
    unsigned short* hp = (unsigned short*)p;   p += (size_t)(N + 1) * 32;
    unsigned short* h1 = (unsigned short*)p;   p += (size_t)N * 32;
    int* staging = (int*)hp;                   // E ints < (N+1)*32 ints
    unsigned int* hp_rowN = (unsigned int*)(hp + (size_t)N * 64);

    float* emb    = (float*)d_out;
    float* logits = emb + (size_t)N * HDIM;

    // ---- CSR build (shared by both conv layers) ----
    binA_count<<<NBLK_A, 256, 0, stream>>>(dst, histg, E, NB, chunk);
    binA_scanblocks<<<NB, NBLK_A, 0, stream>>>(histg, btot);
    binA_scanbuckets<<<1, MAXNB, 0, stream>>>(btot, bucketbase, NB);
    binA_scatter<<<NBLK_A, 256, 0, stream>>>(src, dst, histg, bucketbase, staging, E, NB, chunk);
    binB_finalize<<<NB, 256, 0, stream>>>(staging, bucketbase, rows, esrc, dinv, hp_rowN, N, NB);

    const int gBlocks = (N + 127) / 128;
    const int aBlocks = (N + 31) / 32;

    // ---- layer 1 ----
    gemm1_kernel<<<gBlocks, 256, 0, stream>>>(x, W1, dinv, hp, N);
    agg_kernel<true><<<aBlocks, 256, 0, stream>>>(
        (const uint4*)hp, esrc, rows, dinv, b1, h1, N);

    // ---- layer 2 ----
    gemm2_kernel<<<gBlocks, 256, 0, stream>>>(h1, W2, dinv, hp, N);
    agg_kernel<false><<<aBlocks, 256, 0, stream>>>(
        (const uint4*)hp, esrc, rows, dinv, b2, emb, N);

    // ---- FC head ----
    fc_kernel<<<gBlocks, 256, 0, stream>>>(emb, Wfc, bfc, logits, N);
}